// Round 1
// baseline (234.704 us; speedup 1.0000x reference)
//
#include <hip/hip_runtime.h>
#include <hip/hip_bf16.h>
#include <hip/hip_fp16.h>

// Bahdanau location-sensitive attention, fused f16-MFMA implementation.
// B=32 T=1536 H=1024 CTX=1024 CONV_OUT=32
//
// Pipeline:
//  k_prep_b   : pack [V | U] -> f16 B-matrix [CTX][1056]
//  k_prep_loc : conv1d(last_alignment) -> f16 loc [M][32]  (appended K-block)
//  k_prep_add : dec_proj[b,c] + bias[c]  (f32, tiny GEMV)
//  k_main     : fused GEMM(M=49152,N=1024,K=1056) + tanh + dot(w) -> partial scores
//  k_softmax  : softmax over T per batch -> alignment (output 1)
//  k_ctx_part/k_ctx_red : context = alignment @ enc (output 0)

constexpr int kB = 32, kT = 1536, kH = 1024, kC = 1024, kCO = 32;
constexpr int kM = kB * kT;      // 49152
constexpr int kK = kH + kCO;     // 1056

typedef _Float16 f16;
typedef _Float16 f16x8 __attribute__((ext_vector_type(8)));
typedef float f32x4 __attribute__((ext_vector_type(4)));

// ---- ws layout (bytes) ----
constexpr size_t WS_BF16  = 0;                                  // kC*kK f16   (2.2 MB)
constexpr size_t WS_LOC   = WS_BF16 + (size_t)kC * kK * 2;      // kM*kCO f16  (3 MB)
constexpr size_t WS_ADD   = WS_LOC + (size_t)kM * kCO * 2;      // kB*kC f32
constexpr size_t WS_SCORE = WS_ADD + (size_t)kB * kC * 4;       // 4*kM f32 partial scores
constexpr size_t WS_CTXP  = WS_SCORE + (size_t)4 * kM * 4;      // 8*kB*kH f32
// total ~7.3 MB

// ---------------------------------------------------------------- prep B
__global__ void k_prep_b(const float* __restrict__ V, const float* __restrict__ U,
                         f16* __restrict__ Bf) {
    int idx = blockIdx.x * 256 + threadIdx.x;        // < kC*kK
    int c = idx / kK, k = idx - c * kK;
    float v = (k < kH) ? V[(size_t)c * kH + k] : U[(size_t)c * kCO + (k - kH)];
    Bf[idx] = (f16)v;
}

// ---------------------------------------------------------------- prep loc (conv1d)
__global__ void k_prep_loc(const float* __restrict__ la, const float* __restrict__ cw,
                           const float* __restrict__ cb, f16* __restrict__ loc) {
    int m = blockIdx.x * 256 + threadIdx.x;          // < kM
    int b = m / kT, t = m - b * kT;
    float x0 = (t > 0)      ? la[(size_t)b * kT + t - 1] : 0.f;
    float x1 = la[(size_t)b * kT + t];
    float x2 = (t < kT - 1) ? la[(size_t)b * kT + t + 1] : 0.f;
    union { f16 h[32]; int4 q[4]; } u;
#pragma unroll
    for (int k = 0; k < 32; ++k)
        u.h[k] = (f16)(cw[k * 3] * x0 + cw[k * 3 + 1] * x1 + cw[k * 3 + 2] * x2 + cb[k]);
    int4* dst = (int4*)(loc + (size_t)m * 32);
    dst[0] = u.q[0]; dst[1] = u.q[1]; dst[2] = u.q[2]; dst[3] = u.q[3];
}

// ---------------------------------------------------------------- prep add = dec@W^T + bias
__global__ void k_prep_add(const float* __restrict__ dec, const float* __restrict__ W,
                           const float* __restrict__ bias, float* __restrict__ add) {
    __shared__ float dl[kH];
    int bb = blockIdx.x >> 2;
    int cc = (blockIdx.x & 3) * 256 + threadIdx.x;
    *(float4*)&dl[threadIdx.x * 4] = *(const float4*)&dec[(size_t)bb * kH + threadIdx.x * 4];
    __syncthreads();
    float acc = bias[cc];
    const float* wr = W + (size_t)cc * kH;
    for (int h = 0; h < kH; h += 4) {
        float4 wv = *(const float4*)&wr[h];
        acc += wv.x * dl[h] + wv.y * dl[h + 1] + wv.z * dl[h + 2] + wv.w * dl[h + 3];
    }
    add[(size_t)bb * kC + cc] = acc;
}

// ---------------------------------------------------------------- fused main GEMM
// tile 128(M) x 256(N), 512 threads = 8 waves (2x4), per-wave 64x64, BK=64.
// LDS rows are 128B (64 f16) = 8 slots of 16B; slot ^= (row&7) XOR swizzle.
__launch_bounds__(512)
__global__ void k_main(const float* __restrict__ enc, const f16* __restrict__ Bf,
                       const f16* __restrict__ loc, const float* __restrict__ add,
                       const float* __restrict__ wvec, float* __restrict__ spart) {
    __shared__ __align__(16) f16 As[128 * 64];
    __shared__ __align__(16) f16 Bs[256 * 64];
    __shared__ float add_l[256], w_l[256];
    __shared__ float sred[2][64][4];

    const int tid = threadIdx.x, lane = tid & 63, wave = tid >> 6;
    const int wm = wave >> 2, wn = wave & 3;
    const int mt = blockIdx.x >> 2, nt = blockIdx.x & 3;   // nt fastest -> A-tile L2/L3 reuse
    const int m0 = mt * 128, n0 = nt * 256;
    const int bb = m0 / kT;                                // 1536 % 128 == 0: one batch per tile

    if (tid < 256) {
        add_l[tid] = add[(size_t)bb * kC + n0 + tid];
        w_l[tid]   = wvec[n0 + tid];
    }

    f32x4 acc[4][4];
#pragma unroll
    for (int i = 0; i < 4; ++i)
#pragma unroll
        for (int j = 0; j < 4; ++j) acc[i][j] = (f32x4){0.f, 0.f, 0.f, 0.f};

    const int ar = tid >> 2, aq = tid & 3;   // A stage: 4 thr/row, 16 f32 each
    const int br = tid >> 1, bh = tid & 1;   // B stage: 2 thr/row, 32 f16 each
    const float* ap = enc + (size_t)(m0 + ar) * kH + aq * 16;
    const f16*   bp = Bf + (size_t)(n0 + br) * kK;
    char* aw = (char*)As + ar * 128;
    char* bw = (char*)Bs + br * 128;
    const int axm = ar & 7, bxm = br & 7;

    for (int step = 0; step < 17; ++step) {
        if (step < 16) {
            const int k0 = step * 64;
            float4 f0 = *(const float4*)(ap + k0);
            float4 f1 = *(const float4*)(ap + k0 + 4);
            float4 f2 = *(const float4*)(ap + k0 + 8);
            float4 f3 = *(const float4*)(ap + k0 + 12);
            union { f16 h[16]; int4 q[2]; } pk;
            pk.h[0] = (f16)f0.x;  pk.h[1] = (f16)f0.y;  pk.h[2] = (f16)f0.z;  pk.h[3] = (f16)f0.w;
            pk.h[4] = (f16)f1.x;  pk.h[5] = (f16)f1.y;  pk.h[6] = (f16)f1.z;  pk.h[7] = (f16)f1.w;
            pk.h[8] = (f16)f2.x;  pk.h[9] = (f16)f2.y;  pk.h[10] = (f16)f2.z; pk.h[11] = (f16)f2.w;
            pk.h[12] = (f16)f3.x; pk.h[13] = (f16)f3.y; pk.h[14] = (f16)f3.z; pk.h[15] = (f16)f3.w;
            *(int4*)(aw + (((aq * 2 + 0) ^ axm) * 16)) = pk.q[0];
            *(int4*)(aw + (((aq * 2 + 1) ^ axm) * 16)) = pk.q[1];
            const char* bs = (const char*)(bp + k0 + bh * 32);
#pragma unroll
            for (int j = 0; j < 4; ++j) {
                int4 v = *(const int4*)(bs + j * 16);
                *(int4*)(bw + (((bh * 4 + j) ^ bxm) * 16)) = v;
            }
        } else {
            // K tail: 32 loc columns (already f16) x U columns of Bf
            int4 v = *(const int4*)(loc + (size_t)(m0 + ar) * 32 + aq * 8);
            *(int4*)(aw + ((aq ^ axm) * 16)) = v;
#pragma unroll
            for (int j = 0; j < 2; ++j) {
                int4 w0 = *(const int4*)(bp + kH + (bh * 2 + j) * 8);
                *(int4*)(bw + (((bh * 2 + j) ^ bxm) * 16)) = w0;
            }
        }
        __syncthreads();
        const int nkk = (step < 16) ? 2 : 1;
        for (int kk = 0; kk < nkk; ++kk) {
            f16x8 af[4], bfr[4];
            const int g = lane >> 4, rl = lane & 15;
#pragma unroll
            for (int mi = 0; mi < 4; ++mi) {
                int row = wm * 64 + mi * 16 + rl;
                af[mi] = *(const f16x8*)((const char*)As + row * 128 + (((kk * 4 + g) ^ (row & 7)) * 16));
            }
#pragma unroll
            for (int ni = 0; ni < 4; ++ni) {
                int row = wn * 64 + ni * 16 + rl;
                bfr[ni] = *(const f16x8*)((const char*)Bs + row * 128 + (((kk * 4 + g) ^ (row & 7)) * 16));
            }
#pragma unroll
            for (int mi = 0; mi < 4; ++mi)
#pragma unroll
                for (int ni = 0; ni < 4; ++ni)
                    acc[mi][ni] = __builtin_amdgcn_mfma_f32_16x16x32_f16(af[mi], bfr[ni], acc[mi][ni], 0, 0, 0);
        }
        __syncthreads();
    }

    // epilogue: e = tanh(acc + add[c]); partial score = sum_c e*w[c]
#pragma unroll
    for (int mi = 0; mi < 4; ++mi) {
#pragma unroll
        for (int i = 0; i < 4; ++i) {
            float p = 0.f;
#pragma unroll
            for (int ni = 0; ni < 4; ++ni) {
                int cl = wn * 64 + ni * 16 + (lane & 15);
                float e = tanhf(acc[mi][ni][i] + add_l[cl]);
                p += e * w_l[cl];
            }
            p += __shfl_xor(p, 1);
            p += __shfl_xor(p, 2);
            p += __shfl_xor(p, 4);
            p += __shfl_xor(p, 8);
            if ((lane & 15) == 0)
                sred[wm][mi * 16 + (lane >> 4) * 4 + i][wn] = p;
        }
    }
    __syncthreads();
    if (tid < 128) {
        int r = tid & 63, w2 = tid >> 6;
        float s = sred[w2][r][0] + sred[w2][r][1] + sred[w2][r][2] + sred[w2][r][3];
        spart[(size_t)nt * kM + m0 + tid] = s;
    }
}

// ---------------------------------------------------------------- softmax over T
__global__ void k_softmax(const float* __restrict__ spart, float* __restrict__ out_align) {
    __shared__ float red[256];
    int b = blockIdx.x, tid = threadIdx.x;
    float v[6];
    float mx = -1e30f;
#pragma unroll
    for (int i = 0; i < 6; ++i) {
        size_t idx = (size_t)b * kT + tid + i * 256;
        float s = spart[idx] + spart[kM + idx] + spart[2 * (size_t)kM + idx] + spart[3 * (size_t)kM + idx];
        v[i] = s; mx = fmaxf(mx, s);
    }
    red[tid] = mx; __syncthreads();
    for (int o = 128; o > 0; o >>= 1) { if (tid < o) red[tid] = fmaxf(red[tid], red[tid + o]); __syncthreads(); }
    mx = red[0]; __syncthreads();
    float sum = 0.f;
#pragma unroll
    for (int i = 0; i < 6; ++i) { v[i] = expf(v[i] - mx); sum += v[i]; }
    red[tid] = sum; __syncthreads();
    for (int o = 128; o > 0; o >>= 1) { if (tid < o) red[tid] += red[tid + o]; __syncthreads(); }
    float inv = 1.f / red[0];
#pragma unroll
    for (int i = 0; i < 6; ++i)
        out_align[(size_t)b * kT + tid + i * 256] = v[i] * inv;
}

// ---------------------------------------------------------------- context partials
__global__ void k_ctx_part(const float* __restrict__ enc, const float* __restrict__ align,
                           float* __restrict__ cpart) {
    __shared__ float al[192];
    int ci = blockIdx.x, b = blockIdx.y, tid = threadIdx.x;
    if (tid < 192) al[tid] = align[(size_t)b * kT + ci * 192 + tid];
    __syncthreads();
    float4 acc = {0.f, 0.f, 0.f, 0.f};
    const float* ep = enc + ((size_t)b * kT + (size_t)ci * 192) * kH + tid * 4;
    for (int t = 0; t < 192; ++t) {
        float a = al[t];
        float4 e = *(const float4*)(ep + (size_t)t * kH);
        acc.x += a * e.x; acc.y += a * e.y; acc.z += a * e.z; acc.w += a * e.w;
    }
    *(float4*)&cpart[((size_t)ci * kB + b) * kH + tid * 4] = acc;
}

__global__ void k_ctx_red(const float* __restrict__ cpart, float* __restrict__ out_ctx) {
    int idx = blockIdx.x * 256 + threadIdx.x;   // < kB*kH
    float s = 0.f;
#pragma unroll
    for (int ci = 0; ci < 8; ++ci) s += cpart[(size_t)ci * kB * kH + idx];
    out_ctx[idx] = s;
}

// ---------------------------------------------------------------- launch
extern "C" void kernel_launch(void* const* d_in, const int* in_sizes, int n_in,
                              void* d_out, int out_size, void* d_ws, size_t ws_size,
                              hipStream_t stream) {
    const float* dec  = (const float*)d_in[0];
    const float* enc  = (const float*)d_in[1];
    const float* la   = (const float*)d_in[2];
    const float* W    = (const float*)d_in[3];
    const float* V    = (const float*)d_in[4];
    const float* U    = (const float*)d_in[5];
    const float* bias = (const float*)d_in[6];
    const float* wv   = (const float*)d_in[7];
    const float* cw   = (const float*)d_in[8];
    const float* cb   = (const float*)d_in[9];

    char* ws = (char*)d_ws;
    f16* Bf      = (f16*)(ws + WS_BF16);
    f16* loc     = (f16*)(ws + WS_LOC);
    float* add   = (float*)(ws + WS_ADD);
    float* spart = (float*)(ws + WS_SCORE);
    float* cpart = (float*)(ws + WS_CTXP);

    float* out_ctx   = (float*)d_out;            // (B,H)
    float* out_align = (float*)d_out + kB * kH;  // (B,T)

    hipLaunchKernelGGL(k_prep_b,   dim3(kC * kK / 256), dim3(256), 0, stream, V, U, Bf);
    hipLaunchKernelGGL(k_prep_loc, dim3(kM / 256),      dim3(256), 0, stream, la, cw, cb, loc);
    hipLaunchKernelGGL(k_prep_add, dim3(kB * 4),        dim3(256), 0, stream, dec, W, bias, add);
    hipLaunchKernelGGL(k_main,     dim3((kM / 128) * 4), dim3(512), 0, stream, enc, Bf, loc, add, wv, spart);
    hipLaunchKernelGGL(k_softmax,  dim3(kB),            dim3(256), 0, stream, spart, out_align);
    hipLaunchKernelGGL(k_ctx_part, dim3(8, kB),         dim3(256), 0, stream, enc, out_align, cpart);
    hipLaunchKernelGGL(k_ctx_red,  dim3(kB * kH / 256), dim3(256), 0, stream, cpart, out_ctx);
}